// Round 1
// baseline (695.699 us; speedup 1.0000x reference)
//
#include <hip/hip_runtime.h>
#include <float.h>

// Problem constants (from reference file)
constexpr int C    = 512;          // DIM_CODES
constexpr int K    = 512;          // DICT_SIZE
constexpr int E    = 16;           // EMBED_DIM
constexpr int B    = 512;          // BATCH
constexpr int ROWS = 128;          // batches per block
constexpr int MUS  = C * E;        // 8192, mu row stride

// Each block: one code-dim c, 128 batch rows. 4 waves; each wave processes
// one batch row at a time (32 rows/wave). The wave holds the FULL 512x16
// dict slice for c in registers: lane holds k = lane + 64*i, i in [0,8)
// => 128 VGPRs of dict data, zero LDS traffic for the inner product.
__launch_bounds__(256, 2)
__global__ void vq_kernel(const float* __restrict__ mu,
                          const float* __restrict__ dict,
                          float* __restrict__ z,
                          float* __restrict__ zq,
                          float* __restrict__ oh)
{
    const int c    = blockIdx.x;
    const int b0   = blockIdx.y * ROWS;
    const int tid  = threadIdx.x;
    const int lane = tid & 63;
    const int wave = tid >> 6;

    __shared__ float mu_s[ROWS][E];    // 8 KB

    const float* __restrict__ dbase = dict + (size_t)c * K * E;

    // ---- dict slice -> registers, plus per-code squared norms
    float4 dv[8][4];
    float  nrm[8];
#pragma unroll
    for (int i = 0; i < 8; ++i) {
        const int k = lane + 64 * i;
        const float4* p = reinterpret_cast<const float4*>(dbase + k * E);
        dv[i][0] = p[0]; dv[i][1] = p[1]; dv[i][2] = p[2]; dv[i][3] = p[3];
        float s = dv[i][0].x * dv[i][0].x;
        s = fmaf(dv[i][0].y, dv[i][0].y, s);
        s = fmaf(dv[i][0].z, dv[i][0].z, s);
        s = fmaf(dv[i][0].w, dv[i][0].w, s);
#pragma unroll
        for (int t = 1; t < 4; ++t) {
            s = fmaf(dv[i][t].x, dv[i][t].x, s);
            s = fmaf(dv[i][t].y, dv[i][t].y, s);
            s = fmaf(dv[i][t].z, dv[i][t].z, s);
            s = fmaf(dv[i][t].w, dv[i][t].w, s);
        }
        nrm[i] = s;
    }

    // ---- stage the 128x16 mu sub-block for this (c, chunk) into LDS
    {
        const int r = tid >> 2, q = tid & 3;
#pragma unroll
        for (int rep = 0; rep < 2; ++rep) {
            const int row = r + rep * 64;
            const float4* p = reinterpret_cast<const float4*>(
                mu + (size_t)(b0 + row) * MUS + c * E);
            reinterpret_cast<float4*>(&mu_s[row][0])[q] = p[q];
        }
    }
    __syncthreads();

    for (int j = 0; j < ROWS / 4; ++j) {
        const int bl = wave + 4 * j;
        const int b  = b0 + bl;

        // broadcast-read the 16-float query (same address across lanes: free)
        float4 m[4];
#pragma unroll
        for (int t = 0; t < 4; ++t)
            m[t] = reinterpret_cast<const float4*>(&mu_s[bl][0])[t];

        float nmu = m[0].x * m[0].x;
        nmu = fmaf(m[0].y, m[0].y, nmu);
        nmu = fmaf(m[0].z, m[0].z, nmu);
        nmu = fmaf(m[0].w, m[0].w, nmu);
#pragma unroll
        for (int t = 1; t < 4; ++t) {
            nmu = fmaf(m[t].x, m[t].x, nmu);
            nmu = fmaf(m[t].y, m[t].y, nmu);
            nmu = fmaf(m[t].z, m[t].z, nmu);
            nmu = fmaf(m[t].w, m[t].w, nmu);
        }

        // ---- distances + per-lane argmin (ascending k => first-index ties)
        float dist_v[8];
        float best_d = FLT_MAX;
        int   best_k = K;
#pragma unroll
        for (int i = 0; i < 8; ++i) {
            float acc = dv[i][0].x * m[0].x;
            acc = fmaf(dv[i][0].y, m[0].y, acc);
            acc = fmaf(dv[i][0].z, m[0].z, acc);
            acc = fmaf(dv[i][0].w, m[0].w, acc);
#pragma unroll
            for (int t = 1; t < 4; ++t) {
                acc = fmaf(dv[i][t].x, m[t].x, acc);
                acc = fmaf(dv[i][t].y, m[t].y, acc);
                acc = fmaf(dv[i][t].z, m[t].z, acc);
                acc = fmaf(dv[i][t].w, m[t].w, acc);
            }
            const float dist = fmaf(-2.0f, acc, nmu + nrm[i]);
            dist_v[i] = dist;
            const int k = lane + 64 * i;
            if (dist < best_d) { best_d = dist; best_k = k; }
        }

        // ---- wave argmin with first-index tie-break (matches jnp.argmin)
#pragma unroll
        for (int off = 32; off; off >>= 1) {
            const float od = __shfl_down(best_d, off);
            const int   ok = __shfl_down(best_k, off);
            if (od < best_d || (od == best_d && ok < best_k)) {
                best_d = od; best_k = ok;
            }
        }
        best_k = __shfl(best_k, 0);
        best_d = __shfl(best_d, 0);

        // ---- runner-up distance (excluding best_k) for near-tie detection
        float sec = FLT_MAX;
#pragma unroll
        for (int i = 0; i < 8; ++i) {
            const int k = lane + 64 * i;
            sec = (k != best_k) ? fminf(sec, dist_v[i]) : sec;
        }
#pragma unroll
        for (int off = 32; off; off >>= 1)
            sec = fminf(sec, __shfl_down(sec, off));
        sec = __shfl(sec, 0);

        // ---- rare exact path: fp64 re-evaluation when gap < 1e-3
        if (sec - best_d < 1e-3f) {
            double nmuD = 0.0;
#pragma unroll
            for (int t = 0; t < 4; ++t) {
                nmuD += (double)m[t].x * m[t].x + (double)m[t].y * m[t].y
                      + (double)m[t].z * m[t].z + (double)m[t].w * m[t].w;
            }
            double bd = DBL_MAX;
            int    bk = K;
#pragma unroll
            for (int i = 0; i < 8; ++i) {
                double nd = 0.0, dt = 0.0;
#pragma unroll
                for (int t = 0; t < 4; ++t) {
                    nd += (double)dv[i][t].x * dv[i][t].x
                        + (double)dv[i][t].y * dv[i][t].y
                        + (double)dv[i][t].z * dv[i][t].z
                        + (double)dv[i][t].w * dv[i][t].w;
                    dt += (double)dv[i][t].x * m[t].x
                        + (double)dv[i][t].y * m[t].y
                        + (double)dv[i][t].z * m[t].z
                        + (double)dv[i][t].w * m[t].w;
                }
                const double dist = nmuD + nd - 2.0 * dt;
                const int k = lane + 64 * i;
                if (dist < bd) { bd = dist; bk = k; }
            }
#pragma unroll
            for (int off = 32; off; off >>= 1) {
                const double od = __shfl_down(bd, off);
                const int    ok = __shfl_down(bk, off);
                if (od < bd || (od == bd && ok < bk)) { bd = od; bk = ok; }
            }
            best_k = __shfl(bk, 0);
        }

        // ---- one_hot row: 512 floats, two coalesced float4 stores per lane
        float* ohp = oh + ((size_t)b * C + c) * K;
#pragma unroll
        for (int h = 0; h < 2; ++h) {
            const int kb = h * 256 + lane * 4;
            float4 v;
            v.x = (kb + 0 == best_k) ? 1.0f : 0.0f;
            v.y = (kb + 1 == best_k) ? 1.0f : 0.0f;
            v.z = (kb + 2 == best_k) ? 1.0f : 0.0f;
            v.w = (kb + 3 == best_k) ? 1.0f : 0.0f;
            *reinterpret_cast<float4*>(ohp + kb) = v;
        }

        // ---- z_embed and z = mu + (zq - mu), fp32 op-for-op like reference
        if (lane < E) {
            const float dq = dbase[best_k * E + lane];   // L2-hot
            const float mm = mu_s[bl][lane];
            const size_t o = (size_t)b * MUS + (size_t)c * E + lane;
            zq[o] = dq;
            z[o]  = mm + (dq - mm);
        }
    }
}

extern "C" void kernel_launch(void* const* d_in, const int* in_sizes, int n_in,
                              void* d_out, int out_size, void* d_ws, size_t ws_size,
                              hipStream_t stream)
{
    const float* mu   = (const float*)d_in[0];
    const float* dict = (const float*)d_in[1];

    float* z  = (float*)d_out;                 // (B, C*E)
    float* zq = z  + (size_t)B * C * E;        // (B, C*E)
    float* oh = zq + (size_t)B * C * E;        // (B, C, K)

    dim3 grid(C, B / ROWS);
    vq_kernel<<<grid, 256, 0, stream>>>(mu, dict, z, zq, oh);
}